// Round 1
// baseline (258.894 us; speedup 1.0000x reference)
//
#include <hip/hip_runtime.h>
#include <cstdint>
#include <cstddef>

#define B_N   16
#define G_N   128
#define FD_N  8192
#define BK    64

typedef unsigned short u16;
typedef u16  u16x4 __attribute__((ext_vector_type(4)));
typedef u16  u16x8 __attribute__((ext_vector_type(8)));
typedef __bf16 bf16x8 __attribute__((ext_vector_type(8)));
typedef float f32x16 __attribute__((ext_vector_type(16)));

// ---- ws layout (in floats) ----
#define STATS_SSQ_Q 0
#define STATS_SUM_Q 2048
#define STATS_SSQ_K 4096
#define STATS_SUM_K 6144
#define STATS_SSQ_N 8192
#define STATS_FLOATS 10240
#define RES_OFF   10240          // 16*4 per-batch results (sm, tri, cyc, ce)
#define CRED_OFF  10304          // 16 * 128*256 reduced C
#define PART_OFF  534592         // CRED_OFF + 16*32768; then ksplit*16*32768 partials

__device__ __forceinline__ u16 f2bf(float f) {
    uint32_t u = __float_as_uint(f);
    u += 0x7FFFu + ((u >> 16) & 1u);      // round-to-nearest-even
    return (u16)(u >> 16);
}

// ================= K1: fused bf16 GEMM (C = q @ [k;n]^T per batch, K-split) + row stats =================
__global__ __launch_bounds__(512, 2)
void k_gemm(const float* __restrict__ q, const float* __restrict__ kM,
            const float* __restrict__ nM, float* __restrict__ ws,
            int ksplit, int kc)
{
    __shared__ __align__(16) u16 sA[G_N * BK];      // 16 KB, xor-swizzled
    __shared__ __align__(16) u16 sB[2 * G_N * BK];  // 32 KB

    const int tid = threadIdx.x;
    const int blk = blockIdx.x;
    const int b   = blk / ksplit;
    const int kch = blk - b * ksplit;
    const int niter = kc / BK;

    const size_t mat_off = (size_t)b * G_N * FD_N + (size_t)kch * kc + (size_t)(tid & 15) * 4;
    const float* qp = q  + mat_off;
    const float* kp = kM + mat_off;
    const float* np = nM + mat_off;
    const int r0 = tid >> 4;        // 0..31 base row
    const int c4 = tid & 15;        // float4-column within 64-wide K tile

    float4 la[4], lb[8];
    float aS[4] = {0.f,0.f,0.f,0.f}, aQ[4] = {0.f,0.f,0.f,0.f};
    float bS[8] = {0.f,0.f,0.f,0.f,0.f,0.f,0.f,0.f};
    float bQ[8] = {0.f,0.f,0.f,0.f,0.f,0.f,0.f,0.f};

    // prologue loads (kb = 0)
    #pragma unroll
    for (int i = 0; i < 4; ++i) la[i]   = *(const float4*)(qp + (size_t)(r0 + 32*i) * FD_N);
    #pragma unroll
    for (int i = 0; i < 4; ++i) lb[i]   = *(const float4*)(kp + (size_t)(r0 + 32*i) * FD_N);
    #pragma unroll
    for (int i = 0; i < 4; ++i) lb[4+i] = *(const float4*)(np + (size_t)(r0 + 32*i) * FD_N);

    const int lane  = tid & 63;
    const int wv    = tid >> 6;     // 8 waves
    const int wm    = wv >> 2;      // 0..1 -> 64-row block
    const int wn    = wv & 3;       // 0..3 -> 64-col block
    const int khalf = lane >> 5;
    const int lrow  = lane & 31;

    f32x16 acc[2][2];
    #pragma unroll
    for (int mb = 0; mb < 2; ++mb)
      #pragma unroll
      for (int nb = 0; nb < 2; ++nb)
        #pragma unroll
        for (int e = 0; e < 16; ++e) acc[mb][nb][e] = 0.f;

    // LDS write offsets (u16 units), 16B-chunk xor swizzle by (row & 7)
    int wA[4], wB[8];
    #pragma unroll
    for (int i = 0; i < 4; ++i) { int row = r0 + 32*i; wA[i] = row*BK + (((c4>>1) ^ (row&7))<<3) + ((c4&1)<<2); }
    #pragma unroll
    for (int i = 0; i < 8; ++i) { int row = r0 + 32*i; wB[i] = row*BK + (((c4>>1) ^ (row&7))<<3) + ((c4&1)<<2); }

    const int rA0 = wm*64 + lrow;
    const int rB0 = wn*64 + lrow;

    for (int kb = 0; kb < niter; ++kb) {
        __syncthreads();    // previous iteration's MFMA reads done
        #pragma unroll
        for (int i = 0; i < 4; ++i) {
            float4 v = la[i];
            aS[i] += v.x + v.y + v.z + v.w;
            aQ[i] += v.x*v.x + v.y*v.y + v.z*v.z + v.w*v.w;
            u16x4 h; h[0]=f2bf(v.x); h[1]=f2bf(v.y); h[2]=f2bf(v.z); h[3]=f2bf(v.w);
            *(u16x4*)(sA + wA[i]) = h;
        }
        #pragma unroll
        for (int i = 0; i < 8; ++i) {
            float4 v = lb[i];
            bS[i] += v.x + v.y + v.z + v.w;
            bQ[i] += v.x*v.x + v.y*v.y + v.z*v.z + v.w*v.w;
            u16x4 h; h[0]=f2bf(v.x); h[1]=f2bf(v.y); h[2]=f2bf(v.z); h[3]=f2bf(v.w);
            *(u16x4*)(sB + wB[i]) = h;
        }
        __syncthreads();
        // prefetch next K tile (overlaps MFMA below)
        if (kb + 1 < niter) {
            const float* qn = qp + (kb+1)*BK;
            const float* kn = kp + (kb+1)*BK;
            const float* nn = np + (kb+1)*BK;
            #pragma unroll
            for (int i = 0; i < 4; ++i) la[i]   = *(const float4*)(qn + (size_t)(r0 + 32*i) * FD_N);
            #pragma unroll
            for (int i = 0; i < 4; ++i) lb[i]   = *(const float4*)(kn + (size_t)(r0 + 32*i) * FD_N);
            #pragma unroll
            for (int i = 0; i < 4; ++i) lb[4+i] = *(const float4*)(nn + (size_t)(r0 + 32*i) * FD_N);
        }
        #pragma unroll
        for (int s = 0; s < 4; ++s) {
            int chunk = s*2 + khalf;
            bf16x8 af[2], bf[2];
            #pragma unroll
            for (int mb = 0; mb < 2; ++mb) {
                int row = rA0 + mb*32;
                u16x8 raw = *(const u16x8*)(sA + row*BK + (((chunk) ^ (row&7))<<3));
                af[mb] = __builtin_bit_cast(bf16x8, raw);
            }
            #pragma unroll
            for (int nb = 0; nb < 2; ++nb) {
                int row = rB0 + nb*32;
                u16x8 raw = *(const u16x8*)(sB + row*BK + (((chunk) ^ (row&7))<<3));
                bf[nb] = __builtin_bit_cast(bf16x8, raw);
            }
            #pragma unroll
            for (int mb = 0; mb < 2; ++mb)
              #pragma unroll
              for (int nb = 0; nb < 2; ++nb)
                acc[mb][nb] = __builtin_amdgcn_mfma_f32_32x32x16_bf16(af[mb], bf[nb], acc[mb][nb], 0, 0, 0);
        }
    }

    // partial C write: C/D layout col=lane&31, row=(reg&3)+8*(reg>>2)+4*(lane>>5)
    float* part = ws + PART_OFF + (size_t)blk * (G_N * 256);
    #pragma unroll
    for (int mb = 0; mb < 2; ++mb)
      #pragma unroll
      for (int nb = 0; nb < 2; ++nb) {
        int col = wn*64 + nb*32 + lrow;
        int rbase = wm*64 + mb*32 + 4*khalf;
        #pragma unroll
        for (int reg = 0; reg < 16; ++reg) {
            int row = rbase + (reg & 3) + 8*(reg >> 2);
            part[(size_t)row * 256 + col] = acc[mb][nb][reg];
        }
      }

    // row stats: reduce across the 16 lanes sharing a row, then one atomic
    #pragma unroll
    for (int i = 0; i < 4; ++i) {
        float s = aS[i], qq = aQ[i];
        for (int m = 8; m >= 1; m >>= 1) { s += __shfl_xor(s, m, 64); qq += __shfl_xor(qq, m, 64); }
        if ((lane & 15) == 0) {
            int row = r0 + 32*i;
            atomicAdd(ws + STATS_SUM_Q + b*G_N + row, s);
            atomicAdd(ws + STATS_SSQ_Q + b*G_N + row, qq);
        }
    }
    #pragma unroll
    for (int i = 0; i < 8; ++i) {
        float s = bS[i], qq = bQ[i];
        for (int m = 8; m >= 1; m >>= 1) { s += __shfl_xor(s, m, 64); qq += __shfl_xor(qq, m, 64); }
        if ((lane & 15) == 0) {
            int row = r0 + 32*i;
            if (row < G_N) {
                atomicAdd(ws + STATS_SUM_K + b*G_N + row, s);
                atomicAdd(ws + STATS_SSQ_K + b*G_N + row, qq);
            } else {
                atomicAdd(ws + STATS_SSQ_N + b*G_N + (row - G_N), qq);
            }
        }
    }
}

// ================= K2: sum K-split partials =================
__global__ void k_red(float* __restrict__ ws, int ksplit)
{
    int idx = blockIdx.x * 256 + threadIdx.x;      // 0..524287
    int b = idx >> 15;
    int w = idx & 32767;
    const float* p = ws + PART_OFF + ((size_t)(b * ksplit) << 15);
    float s = 0.f;
    for (int ksi = 0; ksi < ksplit; ++ksi) s += p[((size_t)ksi << 15) + w];
    ws[CRED_OFF + idx] = s;
}

// ================= K3: per-batch loss epilogue =================
__global__ __launch_bounds__(256)
void k_epi(float* __restrict__ ws)
{
    const int b = blockIdx.x;
    const int t = threadIdx.x;
    __shared__ float invq[128], invk[128], invn[128], sqv[128], skv[128], ddq[128], ddk[128];
    __shared__ float rbuf[4][4];

    const float c0 = (float)FD_N * 1e-6f * 1e-6f;   // FD*eps^2

    if (t < 128) {
        float iq = 1.f / fmaxf(sqrtf(ws[STATS_SSQ_Q + b*128 + t]), 1e-12f);
        invq[t] = iq;
        sqv[t]  = ws[STATS_SUM_Q + b*128 + t] * iq;
        float ik = 1.f / fmaxf(sqrtf(ws[STATS_SSQ_K + b*128 + t]), 1e-12f);
        invk[t] = ik;
        skv[t]  = ws[STATS_SUM_K + b*128 + t] * ik;
        invn[t] = 1.f / fmaxf(sqrtf(ws[STATS_SSQ_N + b*128 + t]), 1e-12f);
    }
    __syncthreads();
    const float* C = ws + CRED_OFF + (size_t)b * 32768;   // [128 rows][256 cols], cols 0..127 = k, 128..255 = n
    if (t < 128) {
        float S_ii = C[t*256 + t] * invq[t] * invk[t];
        ddq[t] = sqrtf(fmaxf(2.f - 2.f*S_ii + 2e-6f*(sqv[t]-skv[t]) + c0, 0.f));
        ddk[t] = sqrtf(fmaxf(2.f - 2.f*S_ii + 2e-6f*(skv[t]-sqv[t]) + c0, 0.f));
    }
    __syncthreads();

    float sm = 0.f, tri = 0.f, cyc = 0.f, ce = 0.f;
    for (int idx = t; idx < 16384; idx += 256) {
        int i = idx >> 7, j = idx & 127;
        float S_ij = C[i*256 + j] * invq[i] * invk[j];
        float dd = S_ij - (i == j ? 1.f : 0.f);
        sm += dd * dd;
        if (i != j) {
            // tri1 term (i,j)
            float dqk = sqrtf(fmaxf(2.f - 2.f*S_ij + 2e-6f*(sqv[i]-skv[j]) + c0, 0.f));
            tri += fmaxf(ddq[i] - dqk + 1.f, 0.f);
            // tri2 term reindexed: d_kq[j][i] uses S[i][j]
            float dkq = sqrtf(fmaxf(2.f - 2.f*S_ij + 2e-6f*(skv[j]-sqv[i]) + c0, 0.f));
            tri += fmaxf(ddk[j] - dkq + 1.f, 0.f);
            float S_ji = C[j*256 + i] * invq[j] * invk[i];
            cyc += fabsf(S_ij - S_ji);
        }
    }
    // InfoNCE per row (logits bounded by 1/T=5, no max-shift needed)
    if (t < 128) {
        float iq = invq[t];
        float lp = C[t*256 + t] * iq * invk[t] * 5.0f;
        float ssum = __expf(lp);
        for (int j = 0; j < 128; ++j) {
            float ln = C[t*256 + 128 + j] * iq * invn[j] * 5.0f;
            ssum += __expf(ln);
        }
        ce = __logf(ssum) - lp;
    }

    for (int m = 32; m >= 1; m >>= 1) {
        sm  += __shfl_xor(sm,  m, 64);
        tri += __shfl_xor(tri, m, 64);
        cyc += __shfl_xor(cyc, m, 64);
        ce  += __shfl_xor(ce,  m, 64);
    }
    int wvi = t >> 6, ln0 = t & 63;
    if (ln0 == 0) { rbuf[wvi][0] = sm; rbuf[wvi][1] = tri; rbuf[wvi][2] = cyc; rbuf[wvi][3] = ce; }
    __syncthreads();
    if (t == 0) {
        float SM = 0, TR = 0, CY = 0, CE = 0;
        for (int w2 = 0; w2 < 4; ++w2) { SM += rbuf[w2][0]; TR += rbuf[w2][1]; CY += rbuf[w2][2]; CE += rbuf[w2][3]; }
        float* r = ws + RES_OFF + b*4;
        r[0] = SM / 16384.f;
        r[1] = TR;
        r[2] = CY / (128.f * 127.f);
        r[3] = CE / 16384.f;
    }
}

// ================= K4: final combine (cumsum-weighted tri per the reference's bug) =================
__global__ void k_fin(const float* __restrict__ ws, float* __restrict__ out)
{
    int l = threadIdx.x;
    float v = 0.f;
    if (l < 16) {
        const float* r = ws + RES_OFF + l*4;
        v = r[0] + r[2] + r[3] + (float)(16 - l) * r[1] / 32512.f;   // tri_cnt = 2*128*127
    }
    for (int m = 8; m >= 1; m >>= 1) v += __shfl_xor(v, m, 64);
    if (l == 0) out[0] = v;
}

extern "C" void kernel_launch(void* const* d_in, const int* in_sizes, int n_in,
                              void* d_out, int out_size, void* d_ws, size_t ws_size,
                              hipStream_t stream)
{
    const float* q  = (const float*)d_in[0];
    const float* kM = (const float*)d_in[1];
    const float* nM = (const float*)d_in[2];
    float* ws  = (float*)d_ws;
    float* out = (float*)d_out;

    int ksplit = 16;
    while (ksplit > 1 &&
           ((size_t)PART_OFF + (size_t)ksplit * B_N * 32768) * sizeof(float) > ws_size)
        ksplit >>= 1;
    int kc = FD_N / ksplit;

    hipMemsetAsync(d_ws, 0, STATS_FLOATS * sizeof(float), stream);
    k_gemm<<<B_N * ksplit, 512, 0, stream>>>(q, kM, nM, ws, ksplit, kc);
    k_red<<<(B_N * 32768) / 256, 256, 0, stream>>>(ws, ksplit);
    k_epi<<<B_N, 256, 0, stream>>>(ws);
    k_fin<<<1, 64, 0, stream>>>(ws, out);
}